// Round 1
// 112.952 us; speedup vs baseline: 1.1324x; 1.1324x over previous
//
#include <hip/hip_runtime.h>
#include <math.h>

// Round-12: structural attack on the two measured costs:
//  (a) register-pressure overhead: vx[24]/vy[24] payload moved to LDS
//      ([24][256] float2, slot stride 2048B == 0 mod 128 -> bank index
//      depends only on lane -> minimal 4-way for b64, no extra conflicts;
//      per-thread-private column -> NO barriers). Live set drops to
//      pk[24]+scalars (~50) -> fits 64 arch VGPRs -> no v_accvgpr traffic.
//  (b) 8x24 extract-min (~1100 inst) -> key-only partial sorting network.
//      Extraction order == plain ascending key order (keys span < 2^31,
//      masked keys never wrap below real ones), and keys are UNIQUE (slot
//      id in low 5 bits) -> lowest-8-sorted network output is the exact
//      extraction sequence -> crs sum order identical -> BIT-IDENTICAL.
//      Network: 3x Batcher SORT8 (19 CE) + 2x merge-low-8 (half-cleaner +
//      bitonic-8, 20 CE) = 97 CE = 194 v_min_u32/v_max_u32.
// k>8 tail (rare): serial min over the 16 leftovers; partition property
// guarantees remaining keys all exceed the extracted 8 -> ascending order
// preserved; keys unique so sentinel-removal removes exactly one.
// FROZEN (bit-critical, round-7 lesson): atan2f/cosf/sinf + __f*_rn corner
// chain, mask ratios, masked sx/sy sum order, centroid FDIV, cross order.

#define FMUL __fmul_rn
#define FADD __fadd_rn
#define FSUB __fsub_rn
#define FDIV __fdiv_rn

__device__ __forceinline__ float rcpf_(float x) { return __builtin_amdgcn_rcpf(x); }

// compare-exchange on packed keys: min -> pk[A], max -> pk[B]
#define CE(A,B) do { unsigned _x = pk[A], _y = pk[B]; \
                     pk[A] = _x < _y ? _x : _y; pk[B] = _x < _y ? _y : _x; } while (0)

// Batcher odd-even mergesort of pk[o..o+7], 19 CE (sort4+sort4+merge(4,4))
#define SORT8(o) do { \
    CE(o+0,o+1); CE(o+2,o+3); CE(o+0,o+2); CE(o+1,o+3); CE(o+1,o+2); \
    CE(o+4,o+5); CE(o+6,o+7); CE(o+4,o+6); CE(o+5,o+7); CE(o+5,o+6); \
    CE(o+0,o+4); CE(o+1,o+5); CE(o+2,o+6); CE(o+3,o+7); \
    CE(o+2,o+4); CE(o+3,o+5); \
    CE(o+1,o+2); CE(o+3,o+4); CE(o+5,o+6); } while (0)

// pk[0..7] sorted asc, pk[o..o+7] sorted asc ->
// pk[0..7] = lowest 8 of the 16, sorted. Half-cleaner (8 CE; lows land in
// 0..7 as a bitonic sequence) + bitonic sort-8 (12 CE).
#define MERGE_LOW8(o) do { \
    CE(0,o+7); CE(1,o+6); CE(2,o+5); CE(3,o+4); \
    CE(4,o+3); CE(5,o+2); CE(6,o+1); CE(7,o+0); \
    CE(0,4); CE(1,5); CE(2,6); CE(3,7); \
    CE(0,2); CE(1,3); CE(4,6); CE(5,7); \
    CE(0,1); CE(2,3); CE(4,5); CE(6,7); } while (0)

__global__
__attribute__((amdgpu_flat_work_group_size(256, 256), amdgpu_waves_per_eu(1)))
void riou_kernel(const float* __restrict__ pred,
                 const float* __restrict__ tgt,
                 float* __restrict__ out, int n)
{
    // payload store: slot-major so slot stride = 256*8B = 2048B (== 0 mod
    // 128B bank period) -> bank depends only on lane -> no extra conflicts
    // for either uniform-slot or per-lane-dynamic-slot access.
    __shared__ float2 vlds[24][256];
    const int tid = threadIdx.x;
    int i = blockIdx.x * blockDim.x + tid;
    if (i >= n) return;

    const float2* p2 = (const float2*)(pred + 6 * (size_t)i);
    const float2* q2 = (const float2*)(tgt  + 6 * (size_t)i);
    float2 pa = p2[0], pb = p2[1], pc2 = p2[2];
    float2 qa = q2[0], qb = q2[1], qc2 = q2[2];
    const float px = pa.x, py = pa.y, pw = pb.x, ph = pb.y;
    const float qx = qa.x, qy = qa.y, qw = qb.x, qh = qb.y;

    // bit-critical transcendental sequence — DO NOT substitute identities
    float rad1 = atan2f(pc2.x, pc2.y);
    float cA = cosf(rad1), sA = sinf(rad1);
    float rad2 = atan2f(qc2.x, qc2.y);
    float cB = cosf(rad2), sB = sinf(rad2);

    const float ddx[4] = {0.5f, -0.5f, -0.5f, 0.5f};
    const float ddy[4] = {0.5f, 0.5f, -0.5f, -0.5f};
    float c1x[4], c1y[4], c2x[4], c2y[4];
#pragma unroll
    for (int j = 0; j < 4; j++) {
        float cx = FMUL(ddx[j], pw), cy = FMUL(ddy[j], ph);
        c1x[j] = FADD(FSUB(FMUL(cx, cA), FMUL(cy, sA)), px);
        c1y[j] = FADD(FADD(FMUL(cx, sA), FMUL(cy, cA)), py);
        float dx2 = FMUL(ddx[j], qw), dy2 = FMUL(ddy[j], qh);
        c2x[j] = FADD(FSUB(FMUL(dx2, cB), FMUL(dy2, sB)), qx);
        c2y[j] = FADD(FADD(FMUL(dx2, sB), FMUL(dy2, cB)), qy);
    }

    // enclosing-box diagonal + center distance
    float minx = c1x[0], maxx = c1x[0], miny = c1y[0], maxy = c1y[0];
#pragma unroll
    for (int j = 1; j < 4; j++) {
        minx = fminf(minx, c1x[j]); maxx = fmaxf(maxx, c1x[j]);
        miny = fminf(miny, c1y[j]); maxy = fmaxf(maxy, c1y[j]);
    }
#pragma unroll
    for (int j = 0; j < 4; j++) {
        minx = fminf(minx, c2x[j]); maxx = fmaxf(maxx, c2x[j]);
        miny = fminf(miny, c2y[j]); maxy = fmaxf(maxy, c2y[j]);
    }
    float wcb = FSUB(maxx, minx), hcb = FSUB(maxy, miny);
    float c2d = FADD(FMUL(wcb, wcb), FMUL(hcb, hcb));
    float dxc = FSUB(px, qx), dyc = FSUB(py, qy);
    float d2 = FADD(FMUL(dxc, dxc), FMUL(dyc, dyc));

    // ---- phase 1: 24 candidate slots, mask bits + masked sums ----
    unsigned mbits = 0;
    float sx = 0.0f, sy = 0.0f;
    const float eps = 1e-6f;
    const float hieps = 1.0f + 1e-6f;

    // slots 0-3: c1 corners inside c2 (payload stays in regs: c1x/c1y)
    {
        float ax = c2x[0], ay = c2y[0];
        float abx = FSUB(c2x[1], ax), aby = FSUB(c2y[1], ay);
        float adx = FSUB(c2x[3], ax), ady = FSUB(c2y[3], ay);
        float rab = rcpf_(FADD(FMUL(abx, abx), FMUL(aby, aby)));
        float rad = rcpf_(FADD(FMUL(adx, adx), FMUL(ady, ady)));
#pragma unroll
        for (int j = 0; j < 4; j++) {
            float amx = FSUB(c1x[j], ax), amy = FSUB(c1y[j], ay);
            float pab = FMUL(FADD(FMUL(abx, amx), FMUL(aby, amy)), rab);
            float pad = FMUL(FADD(FMUL(adx, amx), FMUL(ady, amy)), rad);
            int m = (pab > -eps) & (pab < hieps) & (pad > -eps) & (pad < hieps);
            mbits |= (unsigned)m << j;
            sx = FADD(sx, m ? c1x[j] : 0.0f);
            sy = FADD(sy, m ? c1y[j] : 0.0f);
        }
    }
    // slots 4-7: c2 corners inside c1
    {
        float ax = c1x[0], ay = c1y[0];
        float abx = FSUB(c1x[1], ax), aby = FSUB(c1y[1], ay);
        float adx = FSUB(c1x[3], ax), ady = FSUB(c1y[3], ay);
        float rab = rcpf_(FADD(FMUL(abx, abx), FMUL(aby, aby)));
        float rad = rcpf_(FADD(FMUL(adx, adx), FMUL(ady, ady)));
#pragma unroll
        for (int j = 0; j < 4; j++) {
            float amx = FSUB(c2x[j], ax), amy = FSUB(c2y[j], ay);
            float pab = FMUL(FADD(FMUL(abx, amx), FMUL(aby, amy)), rab);
            float pad = FMUL(FADD(FMUL(adx, amx), FMUL(ady, amy)), rad);
            int m = (pab > -eps) & (pab < hieps) & (pad > -eps) & (pad < hieps);
            mbits |= (unsigned)m << (4 + j);
            sx = FADD(sx, m ? c2x[j] : 0.0f);
            sy = FADD(sy, m ? c2y[j] : 0.0f);
        }
    }
    // slots 8-23: edge intersections; den_u = -den_t exactly -> one rcp.
    // Raw (ix,iy) -> LDS (garbage if masked; never gathered: masked keys
    // sort last and act/k gating prevents selection).
    float fex[4], fey[4];
#pragma unroll
    for (int e2 = 0; e2 < 4; e2++) {
        fex[e2] = FSUB(c2x[(e2 + 1) & 3], c2x[e2]);
        fey[e2] = FSUB(c2y[(e2 + 1) & 3], c2y[e2]);
    }
#pragma unroll
    for (int e1 = 0; e1 < 4; e1++) {
        float x1 = c1x[e1], y1 = c1y[e1];
        float ex = FSUB(c1x[(e1 + 1) & 3], x1), ey = FSUB(c1y[(e1 + 1) & 3], y1);
#pragma unroll
        for (int e2 = 0; e2 < 4; e2++) {
            float dx31 = FSUB(c2x[e2], x1), dy31 = FSUB(c2y[e2], y1);
            float num_t = FSUB(FMUL(ex, dy31), FMUL(ey, dx31));
            float den_t = FSUB(FMUL(ey, fex[e2]), FMUL(ex, fey[e2]));
            float rd = rcpf_(den_t);          // den==0 -> inf -> masked below
            float tq = FMUL(num_t, rd);
            float num_u = FSUB(FMUL(fey[e2], dx31), FMUL(fex[e2], dy31));
            float uq = FMUL(num_u, rd);       // == -u exactly
            int m = (tq > 0.0f) & (tq < 1.0f) & (uq < 0.0f) & (uq > -1.0f);
            float ix = FADD(x1, FMUL(tq, ex));   // garbage if masked; gated
            float iy = FADD(y1, FMUL(tq, ey));
            int s = 8 + 4 * e1 + e2;
            vlds[s][tid] = make_float2(ix, iy);
            mbits |= (unsigned)m << s;
            sx = FADD(sx, m ? ix : 0.0f);
            sy = FADD(sy, m ? iy : 0.0f);
        }
    }

    int k = __popc(mbits);

    // centroid (IEEE div: feeds every recentered coordinate — bit-frozen)
    float kk = (float)(k > 0 ? k : 1);
    float mx = FDIV(sx, kk), my = FDIV(sy, kk);

    // ---- phase 2: recenter + u32 packed keys (27-bit angle | 5-bit slot) ----
    unsigned pk[24];
#pragma unroll
    for (int j = 0; j < 24; j++) {
        int m = (mbits >> j) & 1u;
        float rx, ry;
        if (j < 4)      { rx = c1x[j];     ry = c1y[j];     }
        else if (j < 8) { rx = c2x[j - 4]; ry = c2y[j - 4]; }
        else            { float2 v = vlds[j][tid]; rx = v.x; ry = v.y; }
        float wx2 = FSUB(rx, mx);
        float wy2 = FSUB(ry, my);
        vlds[j][tid] = make_float2(wx2, wy2);   // recentered payload
        float dsum = FADD(fabsf(wx2), fabsf(wy2));
        float rs = (dsum > 0.0f) ? FMUL(wx2, rcpf_(dsum)) : 1.0f;
        float keyf = copysignf(FSUB(1.0f, rs), wy2);   // monotone in atan2
        unsigned sb = __float_as_uint(keyf);
        unsigned u = sb ^ (unsigned)(((int)sb >> 31) | (int)0x80000000);
        pk[j] = m ? ((u & 0xFFFFFFE0u) | (unsigned)j)
                  : (0xFFFFFFE0u | (unsigned)j);       // masked: sorts last
    }

    // ---- phase 2.5: partial sort network — lowest 8 sorted into pk[0..7].
    // 97 CE total, 2 VALU (v_min_u32/v_max_u32) each; keys unique ->
    // output order == extract-min order == reference argsort order.
    SORT8(0);
    SORT8(8);
    SORT8(16);
    MERGE_LOW8(8);
    MERGE_LOW8(16);

    // ---- phase 3: gather payload for the 8 smallest, walk the ring ----
    float gxv[8], gyv[8];
#pragma unroll
    for (int s = 0; s < 8; s++) {
        float2 v = vlds[pk[s] & 31u][tid];   // slot id always in [0,24)
        gxv[s] = v.x; gyv[s] = v.y;
    }

    float firstx = 0.0f, firsty = 0.0f, prevx = 0.0f, prevy = 0.0f;
    float crs = 0.0f;
#pragma unroll
    for (int s = 0; s < 8; s++) {
        bool act = s < k;                  // inactive pass: payload -> prev
        float bx = act ? gxv[s] : prevx;
        float by = act ? gyv[s] : prevy;
        if (s == 0) { firstx = bx; firsty = by; }
        else {
            // inactive: cross(prev,prev) = exact IEEE 0 (identical products)
            crs = FADD(crs, FSUB(FMUL(prevx, by), FMUL(prevy, bx)));
        }
        prevx = bx; prevy = by;
    }
    // rare tail: noise masks can push k past the geometric bound of 8.
    // Leftovers in pk[8..23] all exceed pk[7] -> successive minima continue
    // the ascending order; keys unique -> sentinel removal removes one.
    if (k > 8) {
        for (int s = 8; s < k; s++) {
            unsigned mn = pk[8];
#pragma unroll
            for (int j = 9; j < 24; j++) mn = (pk[j] < mn) ? pk[j] : mn;
            float2 v = vlds[mn & 31u][tid];
            crs = FADD(crs, FSUB(FMUL(prevx, v.y), FMUL(prevy, v.x)));
            prevx = v.x; prevy = v.y;
#pragma unroll
            for (int j = 8; j < 24; j++) if (pk[j] == mn) pk[j] = 0xFFFFFFFFu;
        }
    }
    // close the ring
    crs = FADD(crs, FSUB(FMUL(prevx, firsty), FMUL(prevy, firstx)));
    float inter = FMUL(0.5f, fabsf(crs));

    float area1 = FMUL(pw, ph), area2 = FMUL(qw, qh);
    float uni = FSUB(FADD(area1, area2), inter);
    float iou = FMUL(inter, rcpf_(uni));

    out[i] = FADD(FSUB(1.0f, iou), FMUL(d2, rcpf_(c2d)));
}

extern "C" void kernel_launch(void* const* d_in, const int* in_sizes, int n_in,
                              void* d_out, int out_size, void* d_ws, size_t ws_size,
                              hipStream_t stream) {
    const float* pred = (const float*)d_in[0];
    const float* tgt  = (const float*)d_in[1];
    float* out = (float*)d_out;
    int n = in_sizes[0] / 6;
    int block = 256;
    int grid = (n + block - 1) / block;
    riou_kernel<<<grid, block, 0, stream>>>(pred, tgt, out, n);
}